// Round 1
// baseline (5074.083 us; speedup 1.0000x reference)
//
#include <hip/hip_runtime.h>

#define N_NODES 50000
#define N_EDGES 600000
#define N_GRAPHS 512
#define DIM 128
#define NLAYERS 4
#define NCLASSES 10

// ---------------------------------------------------------------------------
// Scatter-add aggregation: agg[dst[e]] += h[src[e]]  (128 ch per edge)
// thread = (edge, float4-chunk). 32 threads cover one edge's 128 channels.
// ---------------------------------------------------------------------------
__global__ __launch_bounds__(256) void scatter_kernel(
    const float* __restrict__ h, const int* __restrict__ src,
    const int* __restrict__ dst, float* __restrict__ agg)
{
    int idx = blockIdx.x * 256 + threadIdx.x;   // < 19.2M, fits int
    if (idx >= N_EDGES * 32) return;
    int e = idx >> 5, q = idx & 31;
    int s = src[e], d = dst[e];
    float4 v = ((const float4*)h)[(size_t)s * 32 + q];
    float* o = agg + (size_t)d * 128 + (size_t)q * 4;
    unsafeAtomicAdd(o + 0, v.x);
    unsafeAtomicAdd(o + 1, v.y);
    unsafeAtomicAdd(o + 2, v.z);
    unsafeAtomicAdd(o + 3, v.w);
}

// ---------------------------------------------------------------------------
// Fused GIN MLP: z0 = (1+eps)*h + agg ; t = relu(z0@W1+b1) ; z = t@W2+b2
// Also accumulates per-channel sum / sumsq (BN stats) via global atomics.
// Tile: 32 nodes/block, 256 threads, 4 nodes x 4 channels per thread.
// z (in) holds agg; overwritten in-place with the MLP output.
// ---------------------------------------------------------------------------
__global__ __launch_bounds__(256) void mlp_kernel(
    const float* __restrict__ h, float* __restrict__ z,
    const float* __restrict__ W1, const float* __restrict__ b1,
    const float* __restrict__ W2, const float* __restrict__ b2,
    const float* __restrict__ epsP, float* __restrict__ stats)
{
    __shared__ float zs[32][129];   // [node][ch], +1 pad
    __shared__ float ts[32][129];
    __shared__ float ws[32 * 128];  // 32-k chunk of W

    const int t   = threadIdx.x;
    const int col = t & 31;        // channel group: ch = col*4 .. +3
    const int row = t >> 5;        // node group:    n  = row*4 .. +3
    const int base = blockIdx.x * 32;
    const float epsv = 1.0f + epsP[0];

    // ---- load z0 tile ----
    #pragma unroll
    for (int i = 0; i < 4; i++) {
        int nn = i * 8 + row;
        int n = base + nn;
        if (n < N_NODES) {
            float4 hv = ((const float4*)h)[(size_t)n * 32 + col];
            float4 av = ((const float4*)z)[(size_t)n * 32 + col];
            zs[nn][col * 4 + 0] = epsv * hv.x + av.x;
            zs[nn][col * 4 + 1] = epsv * hv.y + av.y;
            zs[nn][col * 4 + 2] = epsv * hv.z + av.z;
            zs[nn][col * 4 + 3] = epsv * hv.w + av.w;
        } else {
            zs[nn][col * 4 + 0] = 0.f;
            zs[nn][col * 4 + 1] = 0.f;
            zs[nn][col * 4 + 2] = 0.f;
            zs[nn][col * 4 + 3] = 0.f;
        }
    }

    float acc[4][4];
    #pragma unroll
    for (int j = 0; j < 4; j++)
        #pragma unroll
        for (int c = 0; c < 4; c++) acc[j][c] = 0.f;

    // ---- GEMM1: acc = z0 @ W1 ----
    for (int kk = 0; kk < 128; kk += 32) {
        __syncthreads();   // also covers the zs-load on first iteration
        #pragma unroll
        for (int i = 0; i < 4; i++) {
            int f = t + i * 256;
            ((float4*)ws)[f] = ((const float4*)(W1 + (size_t)kk * 128))[f];
        }
        __syncthreads();
        #pragma unroll
        for (int k = 0; k < 32; k++) {
            float4 wv = ((const float4*)(ws + k * 128))[col];
            float z0 = zs[row * 4 + 0][kk + k];
            float z1 = zs[row * 4 + 1][kk + k];
            float z2 = zs[row * 4 + 2][kk + k];
            float z3 = zs[row * 4 + 3][kk + k];
            acc[0][0] += z0 * wv.x; acc[0][1] += z0 * wv.y; acc[0][2] += z0 * wv.z; acc[0][3] += z0 * wv.w;
            acc[1][0] += z1 * wv.x; acc[1][1] += z1 * wv.y; acc[1][2] += z1 * wv.z; acc[1][3] += z1 * wv.w;
            acc[2][0] += z2 * wv.x; acc[2][1] += z2 * wv.y; acc[2][2] += z2 * wv.z; acc[2][3] += z2 * wv.w;
            acc[3][0] += z3 * wv.x; acc[3][1] += z3 * wv.y; acc[3][2] += z3 * wv.z; acc[3][3] += z3 * wv.w;
        }
    }

    // ---- bias + relu -> ts ----
    {
        float4 b1v = ((const float4*)b1)[col];
        float bb[4] = {b1v.x, b1v.y, b1v.z, b1v.w};
        #pragma unroll
        for (int j = 0; j < 4; j++)
            #pragma unroll
            for (int c = 0; c < 4; c++) {
                float v = acc[j][c] + bb[c];
                ts[row * 4 + j][col * 4 + c] = v > 0.f ? v : 0.f;
                acc[j][c] = 0.f;
            }
    }

    // ---- GEMM2: acc = t @ W2 ----
    for (int kk = 0; kk < 128; kk += 32) {
        __syncthreads();   // waits for ts writes / prior ws readers
        #pragma unroll
        for (int i = 0; i < 4; i++) {
            int f = t + i * 256;
            ((float4*)ws)[f] = ((const float4*)(W2 + (size_t)kk * 128))[f];
        }
        __syncthreads();
        #pragma unroll
        for (int k = 0; k < 32; k++) {
            float4 wv = ((const float4*)(ws + k * 128))[col];
            float t0 = ts[row * 4 + 0][kk + k];
            float t1 = ts[row * 4 + 1][kk + k];
            float t2 = ts[row * 4 + 2][kk + k];
            float t3 = ts[row * 4 + 3][kk + k];
            acc[0][0] += t0 * wv.x; acc[0][1] += t0 * wv.y; acc[0][2] += t0 * wv.z; acc[0][3] += t0 * wv.w;
            acc[1][0] += t1 * wv.x; acc[1][1] += t1 * wv.y; acc[1][2] += t1 * wv.z; acc[1][3] += t1 * wv.w;
            acc[2][0] += t2 * wv.x; acc[2][1] += t2 * wv.y; acc[2][2] += t2 * wv.z; acc[2][3] += t2 * wv.w;
            acc[3][0] += t3 * wv.x; acc[3][1] += t3 * wv.y; acc[3][2] += t3 * wv.z; acc[3][3] += t3 * wv.w;
        }
    }

    // ---- bias, store z, per-thread BN partials ----
    float4 b2v = ((const float4*)b2)[col];
    float colsum[4] = {0.f, 0.f, 0.f, 0.f};
    float colsq[4]  = {0.f, 0.f, 0.f, 0.f};
    #pragma unroll
    for (int j = 0; j < 4; j++) {
        int n = base + row * 4 + j;
        float v0 = acc[j][0] + b2v.x;
        float v1 = acc[j][1] + b2v.y;
        float v2 = acc[j][2] + b2v.z;
        float v3 = acc[j][3] + b2v.w;
        if (n < N_NODES) {
            float4 o; o.x = v0; o.y = v1; o.z = v2; o.w = v3;
            ((float4*)z)[(size_t)n * 32 + col] = o;
            colsum[0] += v0; colsq[0] += v0 * v0;
            colsum[1] += v1; colsq[1] += v1 * v1;
            colsum[2] += v2; colsq[2] += v2 * v2;
            colsum[3] += v3; colsq[3] += v3 * v3;
        }
    }

    // ---- block reduction of BN partials (reuse zs as scratch) ----
    __syncthreads();
    float* sc = &zs[0][0];   // 4128 floats available, need 2048
    #pragma unroll
    for (int c = 0; c < 4; c++) {
        sc[row * 128 + col * 4 + c]        = colsum[c];
        sc[1024 + row * 128 + col * 4 + c] = colsq[c];
    }
    __syncthreads();
    if (t < 128) {
        float s = 0.f, q2 = 0.f;
        #pragma unroll
        for (int r = 0; r < 8; r++) {
            s  += sc[r * 128 + t];
            q2 += sc[1024 + r * 128 + t];
        }
        unsafeAtomicAdd(&stats[t], s);
        unsafeAtomicAdd(&stats[128 + t], q2);
    }
}

// ---------------------------------------------------------------------------
// BN apply (training stats) + ReLU + write h + global_add_pool atomics
// ---------------------------------------------------------------------------
__global__ __launch_bounds__(256) void bnpool_kernel(
    const float* __restrict__ z, const float* __restrict__ stats,
    const float* __restrict__ gamma, const float* __restrict__ beta,
    const int* __restrict__ batch, float* __restrict__ hout,
    float* __restrict__ pools, int layer)
{
    int idx = blockIdx.x * 256 + threadIdx.x;
    if (idx >= N_NODES * 32) return;
    int n = idx >> 5, q = idx & 31;
    float4 zv = ((const float4*)z)[(size_t)n * 32 + q];
    float4 s  = ((const float4*)stats)[q];
    float4 sq = ((const float4*)stats)[32 + q];
    float4 gm = ((const float4*)gamma)[q];
    float4 bt = ((const float4*)beta)[q];
    const float invN = 1.0f / (float)N_NODES;
    float4 hv;
    float m, vr, scl, v;
    m = s.x * invN; vr = sq.x * invN - m * m; scl = gm.x * rsqrtf(vr + 1e-5f);
    v = (zv.x - m) * scl + bt.x; hv.x = v > 0.f ? v : 0.f;
    m = s.y * invN; vr = sq.y * invN - m * m; scl = gm.y * rsqrtf(vr + 1e-5f);
    v = (zv.y - m) * scl + bt.y; hv.y = v > 0.f ? v : 0.f;
    m = s.z * invN; vr = sq.z * invN - m * m; scl = gm.z * rsqrtf(vr + 1e-5f);
    v = (zv.z - m) * scl + bt.z; hv.z = v > 0.f ? v : 0.f;
    m = s.w * invN; vr = sq.w * invN - m * m; scl = gm.w * rsqrtf(vr + 1e-5f);
    v = (zv.w - m) * scl + bt.w; hv.w = v > 0.f ? v : 0.f;

    ((float4*)hout)[(size_t)n * 32 + q] = hv;

    int b = batch[n];
    float* p = pools + (size_t)b * (DIM * NLAYERS) + (size_t)layer * DIM + (size_t)q * 4;
    unsafeAtomicAdd(p + 0, hv.x);
    unsafeAtomicAdd(p + 1, hv.y);
    unsafeAtomicAdd(p + 2, hv.z);
    unsafeAtomicAdd(p + 3, hv.w);
}

// ---------------------------------------------------------------------------
// Final linear head: out[g][o] = xcat[g] . Wlin[:,o] + blin[o]
// ---------------------------------------------------------------------------
__global__ __launch_bounds__(256) void final_kernel(
    const float* __restrict__ pools, const float* __restrict__ Wlin,
    const float* __restrict__ blin, float* __restrict__ out)
{
    int idx = blockIdx.x * 256 + threadIdx.x;
    if (idx >= N_GRAPHS * NCLASSES) return;
    int g = idx / NCLASSES, o = idx % NCLASSES;
    const float* xr = pools + (size_t)g * (DIM * NLAYERS);
    float acc = blin[o];
    for (int k = 0; k < DIM * NLAYERS; k++)
        acc += xr[k] * Wlin[(size_t)k * NCLASSES + o];
    out[idx] = acc;
}

// ---------------------------------------------------------------------------
extern "C" void kernel_launch(void* const* d_in, const int* in_sizes, int n_in,
                              void* d_out, int out_size, void* d_ws, size_t ws_size,
                              hipStream_t stream)
{
    const float* x     = (const float*)d_in[0];
    const int*   src   = (const int*)d_in[1];
    const int*   dst   = ((const int*)d_in[1]) + N_EDGES;
    const int*   batch = (const int*)d_in[2];
    const float* W1    = (const float*)d_in[3];
    const float* b1    = (const float*)d_in[4];
    const float* W2    = (const float*)d_in[5];
    const float* b2    = (const float*)d_in[6];
    const float* eps   = (const float*)d_in[7];
    const float* gamma = (const float*)d_in[8];
    const float* beta  = (const float*)d_in[9];
    const float* Wlin  = (const float*)d_in[10];
    const float* blin  = (const float*)d_in[11];
    float* out = (float*)d_out;

    char* ws = (char*)d_ws;
    const size_t FEAT = (size_t)N_NODES * DIM * sizeof(float);       // 25.6 MB
    float* buf_h = (float*)(ws);                                      // h
    float* buf_z = (float*)(ws + FEAT);                               // agg / z
    float* pools = (float*)(ws + 2 * FEAT);                           // 1 MB
    float* stats = (float*)(ws + 2 * FEAT +
                            (size_t)N_GRAPHS * DIM * NLAYERS * sizeof(float));

    // zero pools + stats (contiguous)
    hipMemsetAsync(pools, 0,
                   (size_t)N_GRAPHS * DIM * NLAYERS * sizeof(float) +
                   (size_t)NLAYERS * 256 * sizeof(float), stream);

    for (int l = 0; l < NLAYERS; l++) {
        const float* hin = (l == 0) ? x : buf_h;
        hipMemsetAsync(buf_z, 0, FEAT, stream);
        scatter_kernel<<<(N_EDGES * 32 + 255) / 256, 256, 0, stream>>>(
            hin, src, dst, buf_z);
        mlp_kernel<<<(N_NODES + 31) / 32, 256, 0, stream>>>(
            hin, buf_z,
            W1 + (size_t)l * DIM * DIM, b1 + (size_t)l * DIM,
            W2 + (size_t)l * DIM * DIM, b2 + (size_t)l * DIM,
            eps + l, stats + (size_t)l * 256);
        bnpool_kernel<<<(N_NODES * 32 + 255) / 256, 256, 0, stream>>>(
            buf_z, stats + (size_t)l * 256,
            gamma + (size_t)l * DIM, beta + (size_t)l * DIM,
            batch, buf_h, pools, l);
    }
    final_kernel<<<(N_GRAPHS * NCLASSES + 255) / 256, 256, 0, stream>>>(
        pools, Wlin, blin, out);
}

// Round 2
// 1373.096 us; speedup vs baseline: 3.6954x; 3.6954x over previous
//
#include <hip/hip_runtime.h>

#define N_NODES 50000
#define N_EDGES 600000
#define N_GRAPHS 512
#define DIM 128
#define NLAYERS 4
#define NCLASSES 10

// ---------------------------------------------------------------------------
// CSR build step 1: in-degree histogram
// ---------------------------------------------------------------------------
__global__ __launch_bounds__(256) void hist_kernel(
    const int* __restrict__ dst, int* __restrict__ deg)
{
    int e = blockIdx.x * 256 + threadIdx.x;
    if (e >= N_EDGES) return;
    atomicAdd(&deg[dst[e]], 1);
}

// ---------------------------------------------------------------------------
// CSR build step 2: exclusive scan of deg -> rowptr (and cursor copy).
// Single block of 1024 threads; each thread owns a contiguous chunk.
// ---------------------------------------------------------------------------
__global__ __launch_bounds__(1024) void scan_kernel(
    const int* __restrict__ deg, int* __restrict__ rowptr,
    int* __restrict__ cursor)
{
    __shared__ int sums[1024];
    const int CH = (N_NODES + 1023) / 1024;   // 49
    int t = threadIdx.x;
    int begin = t * CH;
    int end = begin + CH; if (end > N_NODES) end = N_NODES;
    int s = 0;
    for (int i = begin; i < end; i++) s += deg[i];
    sums[t] = s;
    __syncthreads();
    // Hillis-Steele inclusive scan
    for (int off = 1; off < 1024; off <<= 1) {
        int v = (t >= off) ? sums[t - off] : 0;
        __syncthreads();
        sums[t] += v;
        __syncthreads();
    }
    int run = (t == 0) ? 0 : sums[t - 1];
    for (int i = begin; i < end; i++) {
        rowptr[i] = run;
        cursor[i] = run;
        run += deg[i];
    }
    if (t == 1023) rowptr[N_NODES] = run;
}

// ---------------------------------------------------------------------------
// CSR build step 3: scatter edge src ids into their dst's row
// ---------------------------------------------------------------------------
__global__ __launch_bounds__(256) void fill_kernel(
    const int* __restrict__ src, const int* __restrict__ dst,
    int* __restrict__ cursor, int* __restrict__ csr)
{
    int e = blockIdx.x * 256 + threadIdx.x;
    if (e >= N_EDGES) return;
    int p = atomicAdd(&cursor[dst[e]], 1);
    csr[p] = src[e];
}

// ---------------------------------------------------------------------------
// Pull-aggregation + GIN self term:  z0[n] = (1+eps)*h[n] + sum_{s in N(n)} h[s]
// 256 threads = 8 nodes/block, 32 lanes (float4 each) per node. No atomics.
// ---------------------------------------------------------------------------
__global__ __launch_bounds__(256) void gather_kernel(
    const float* __restrict__ h, const int* __restrict__ rowptr,
    const int* __restrict__ csr, const float* __restrict__ epsP,
    float* __restrict__ z)
{
    int t = threadIdx.x;
    int n = blockIdx.x * 8 + (t >> 5);
    int q = t & 31;
    if (n >= N_NODES) return;
    int beg = rowptr[n], end = rowptr[n + 1];
    float e1 = 1.0f + epsP[0];
    float4 acc = ((const float4*)h)[(size_t)n * 32 + q];
    acc.x *= e1; acc.y *= e1; acc.z *= e1; acc.w *= e1;
    int e = beg;
    // 2-way unrolled for two outstanding gathers
    for (; e + 1 < end; e += 2) {
        int s0 = csr[e], s1 = csr[e + 1];
        float4 v0 = ((const float4*)h)[(size_t)s0 * 32 + q];
        float4 v1 = ((const float4*)h)[(size_t)s1 * 32 + q];
        acc.x += v0.x + v1.x; acc.y += v0.y + v1.y;
        acc.z += v0.z + v1.z; acc.w += v0.w + v1.w;
    }
    if (e < end) {
        int s0 = csr[e];
        float4 v0 = ((const float4*)h)[(size_t)s0 * 32 + q];
        acc.x += v0.x; acc.y += v0.y; acc.z += v0.z; acc.w += v0.w;
    }
    ((float4*)z)[(size_t)n * 32 + q] = acc;
}

// ---------------------------------------------------------------------------
// Fused GIN MLP: t = relu(z0@W1+b1) ; z = t@W2+b2  (z0 read from z, in-place)
// Also accumulates per-channel sum / sumsq (BN stats) via global atomics.
// Tile: 32 nodes/block, 256 threads, 4 nodes x 4 channels per thread.
// ---------------------------------------------------------------------------
__global__ __launch_bounds__(256) void mlp_kernel(
    float* __restrict__ z,
    const float* __restrict__ W1, const float* __restrict__ b1,
    const float* __restrict__ W2, const float* __restrict__ b2,
    float* __restrict__ stats)
{
    __shared__ float zs[32][129];   // [node][ch], +1 pad
    __shared__ float ts[32][129];
    __shared__ float ws[32 * 128];  // 32-k chunk of W

    const int t   = threadIdx.x;
    const int col = t & 31;        // channel group: ch = col*4 .. +3
    const int row = t >> 5;        // node group
    const int base = blockIdx.x * 32;

    // ---- load z0 tile ----
    #pragma unroll
    for (int i = 0; i < 4; i++) {
        int nn = i * 8 + row;
        int n = base + nn;
        if (n < N_NODES) {
            float4 av = ((const float4*)z)[(size_t)n * 32 + col];
            zs[nn][col * 4 + 0] = av.x;
            zs[nn][col * 4 + 1] = av.y;
            zs[nn][col * 4 + 2] = av.z;
            zs[nn][col * 4 + 3] = av.w;
        } else {
            zs[nn][col * 4 + 0] = 0.f;
            zs[nn][col * 4 + 1] = 0.f;
            zs[nn][col * 4 + 2] = 0.f;
            zs[nn][col * 4 + 3] = 0.f;
        }
    }

    float acc[4][4];
    #pragma unroll
    for (int j = 0; j < 4; j++)
        #pragma unroll
        for (int c = 0; c < 4; c++) acc[j][c] = 0.f;

    // ---- GEMM1: acc = z0 @ W1 ----
    for (int kk = 0; kk < 128; kk += 32) {
        __syncthreads();
        #pragma unroll
        for (int i = 0; i < 4; i++) {
            int f = t + i * 256;
            ((float4*)ws)[f] = ((const float4*)(W1 + (size_t)kk * 128))[f];
        }
        __syncthreads();
        #pragma unroll
        for (int k = 0; k < 32; k++) {
            float4 wv = ((const float4*)(ws + k * 128))[col];
            float z0 = zs[row * 4 + 0][kk + k];
            float z1 = zs[row * 4 + 1][kk + k];
            float z2 = zs[row * 4 + 2][kk + k];
            float z3 = zs[row * 4 + 3][kk + k];
            acc[0][0] += z0 * wv.x; acc[0][1] += z0 * wv.y; acc[0][2] += z0 * wv.z; acc[0][3] += z0 * wv.w;
            acc[1][0] += z1 * wv.x; acc[1][1] += z1 * wv.y; acc[1][2] += z1 * wv.z; acc[1][3] += z1 * wv.w;
            acc[2][0] += z2 * wv.x; acc[2][1] += z2 * wv.y; acc[2][2] += z2 * wv.z; acc[2][3] += z2 * wv.w;
            acc[3][0] += z3 * wv.x; acc[3][1] += z3 * wv.y; acc[3][2] += z3 * wv.z; acc[3][3] += z3 * wv.w;
        }
    }

    // ---- bias + relu -> ts ----
    {
        float4 b1v = ((const float4*)b1)[col];
        float bb[4] = {b1v.x, b1v.y, b1v.z, b1v.w};
        #pragma unroll
        for (int j = 0; j < 4; j++)
            #pragma unroll
            for (int c = 0; c < 4; c++) {
                float v = acc[j][c] + bb[c];
                ts[row * 4 + j][col * 4 + c] = v > 0.f ? v : 0.f;
                acc[j][c] = 0.f;
            }
    }

    // ---- GEMM2: acc = t @ W2 ----
    for (int kk = 0; kk < 128; kk += 32) {
        __syncthreads();
        #pragma unroll
        for (int i = 0; i < 4; i++) {
            int f = t + i * 256;
            ((float4*)ws)[f] = ((const float4*)(W2 + (size_t)kk * 128))[f];
        }
        __syncthreads();
        #pragma unroll
        for (int k = 0; k < 32; k++) {
            float4 wv = ((const float4*)(ws + k * 128))[col];
            float t0 = ts[row * 4 + 0][kk + k];
            float t1 = ts[row * 4 + 1][kk + k];
            float t2 = ts[row * 4 + 2][kk + k];
            float t3 = ts[row * 4 + 3][kk + k];
            acc[0][0] += t0 * wv.x; acc[0][1] += t0 * wv.y; acc[0][2] += t0 * wv.z; acc[0][3] += t0 * wv.w;
            acc[1][0] += t1 * wv.x; acc[1][1] += t1 * wv.y; acc[1][2] += t1 * wv.z; acc[1][3] += t1 * wv.w;
            acc[2][0] += t2 * wv.x; acc[2][1] += t2 * wv.y; acc[2][2] += t2 * wv.z; acc[2][3] += t2 * wv.w;
            acc[3][0] += t3 * wv.x; acc[3][1] += t3 * wv.y; acc[3][2] += t3 * wv.z; acc[3][3] += t3 * wv.w;
        }
    }

    // ---- bias, store z, per-thread BN partials ----
    float4 b2v = ((const float4*)b2)[col];
    float colsum[4] = {0.f, 0.f, 0.f, 0.f};
    float colsq[4]  = {0.f, 0.f, 0.f, 0.f};
    #pragma unroll
    for (int j = 0; j < 4; j++) {
        int n = base + row * 4 + j;
        float v0 = acc[j][0] + b2v.x;
        float v1 = acc[j][1] + b2v.y;
        float v2 = acc[j][2] + b2v.z;
        float v3 = acc[j][3] + b2v.w;
        if (n < N_NODES) {
            float4 o; o.x = v0; o.y = v1; o.z = v2; o.w = v3;
            ((float4*)z)[(size_t)n * 32 + col] = o;
            colsum[0] += v0; colsq[0] += v0 * v0;
            colsum[1] += v1; colsq[1] += v1 * v1;
            colsum[2] += v2; colsq[2] += v2 * v2;
            colsum[3] += v3; colsq[3] += v3 * v3;
        }
    }

    // ---- block reduction of BN partials (reuse zs as scratch) ----
    __syncthreads();
    float* sc = &zs[0][0];
    #pragma unroll
    for (int c = 0; c < 4; c++) {
        sc[row * 128 + col * 4 + c]        = colsum[c];
        sc[1024 + row * 128 + col * 4 + c] = colsq[c];
    }
    __syncthreads();
    if (t < 128) {
        float s = 0.f, q2 = 0.f;
        #pragma unroll
        for (int r = 0; r < 8; r++) {
            s  += sc[r * 128 + t];
            q2 += sc[1024 + r * 128 + t];
        }
        unsafeAtomicAdd(&stats[t], s);
        unsafeAtomicAdd(&stats[128 + t], q2);
    }
}

// ---------------------------------------------------------------------------
// BN apply (training stats) + ReLU + write h + global_add_pool atomics
// ---------------------------------------------------------------------------
__global__ __launch_bounds__(256) void bnpool_kernel(
    const float* __restrict__ z, const float* __restrict__ stats,
    const float* __restrict__ gamma, const float* __restrict__ beta,
    const int* __restrict__ batch, float* __restrict__ hout,
    float* __restrict__ pools, int layer)
{
    int idx = blockIdx.x * 256 + threadIdx.x;
    if (idx >= N_NODES * 32) return;
    int n = idx >> 5, q = idx & 31;
    float4 zv = ((const float4*)z)[(size_t)n * 32 + q];
    float4 s  = ((const float4*)stats)[q];
    float4 sq = ((const float4*)stats)[32 + q];
    float4 gm = ((const float4*)gamma)[q];
    float4 bt = ((const float4*)beta)[q];
    const float invN = 1.0f / (float)N_NODES;
    float4 hv;
    float m, vr, scl, v;
    m = s.x * invN; vr = sq.x * invN - m * m; scl = gm.x * rsqrtf(vr + 1e-5f);
    v = (zv.x - m) * scl + bt.x; hv.x = v > 0.f ? v : 0.f;
    m = s.y * invN; vr = sq.y * invN - m * m; scl = gm.y * rsqrtf(vr + 1e-5f);
    v = (zv.y - m) * scl + bt.y; hv.y = v > 0.f ? v : 0.f;
    m = s.z * invN; vr = sq.z * invN - m * m; scl = gm.z * rsqrtf(vr + 1e-5f);
    v = (zv.z - m) * scl + bt.z; hv.z = v > 0.f ? v : 0.f;
    m = s.w * invN; vr = sq.w * invN - m * m; scl = gm.w * rsqrtf(vr + 1e-5f);
    v = (zv.w - m) * scl + bt.w; hv.w = v > 0.f ? v : 0.f;

    ((float4*)hout)[(size_t)n * 32 + q] = hv;

    int b = batch[n];
    float* p = pools + (size_t)b * (DIM * NLAYERS) + (size_t)layer * DIM + (size_t)q * 4;
    unsafeAtomicAdd(p + 0, hv.x);
    unsafeAtomicAdd(p + 1, hv.y);
    unsafeAtomicAdd(p + 2, hv.z);
    unsafeAtomicAdd(p + 3, hv.w);
}

// ---------------------------------------------------------------------------
// Final linear head
// ---------------------------------------------------------------------------
__global__ __launch_bounds__(256) void final_kernel(
    const float* __restrict__ pools, const float* __restrict__ Wlin,
    const float* __restrict__ blin, float* __restrict__ out)
{
    int idx = blockIdx.x * 256 + threadIdx.x;
    if (idx >= N_GRAPHS * NCLASSES) return;
    int g = idx / NCLASSES, o = idx % NCLASSES;
    const float* xr = pools + (size_t)g * (DIM * NLAYERS);
    float acc = blin[o];
    for (int k = 0; k < DIM * NLAYERS; k++)
        acc += xr[k] * Wlin[(size_t)k * NCLASSES + o];
    out[idx] = acc;
}

// ---------------------------------------------------------------------------
extern "C" void kernel_launch(void* const* d_in, const int* in_sizes, int n_in,
                              void* d_out, int out_size, void* d_ws, size_t ws_size,
                              hipStream_t stream)
{
    const float* x     = (const float*)d_in[0];
    const int*   src   = (const int*)d_in[1];
    const int*   dst   = ((const int*)d_in[1]) + N_EDGES;
    const int*   batch = (const int*)d_in[2];
    const float* W1    = (const float*)d_in[3];
    const float* b1    = (const float*)d_in[4];
    const float* W2    = (const float*)d_in[5];
    const float* b2    = (const float*)d_in[6];
    const float* eps   = (const float*)d_in[7];
    const float* gamma = (const float*)d_in[8];
    const float* beta  = (const float*)d_in[9];
    const float* Wlin  = (const float*)d_in[10];
    const float* blin  = (const float*)d_in[11];
    float* out = (float*)d_out;

    char* ws = (char*)d_ws;
    const size_t FEAT = (size_t)N_NODES * DIM * sizeof(float);       // 25.6 MB
    size_t off = 0;
    float* buf_h  = (float*)(ws + off); off += FEAT;
    float* buf_z  = (float*)(ws + off); off += FEAT;
    float* pools  = (float*)(ws + off); off += (size_t)N_GRAPHS * DIM * NLAYERS * sizeof(float);
    float* stats  = (float*)(ws + off); off += (size_t)NLAYERS * 256 * sizeof(float);
    int*   deg    = (int*)(ws + off);   off += (size_t)N_NODES * sizeof(int);      // also "cursor"
    int*   rowptr = (int*)(ws + off);   off += (size_t)(N_NODES + 1) * sizeof(int) + 12;
    int*   csr    = (int*)(ws + off);   off += (size_t)N_EDGES * sizeof(int);

    // zero pools + stats (contiguous) and deg
    hipMemsetAsync(pools, 0,
                   (size_t)N_GRAPHS * DIM * NLAYERS * sizeof(float) +
                   (size_t)NLAYERS * 256 * sizeof(float), stream);
    hipMemsetAsync(deg, 0, (size_t)N_NODES * sizeof(int), stream);

    // ---- build CSR once (reused across all 4 layers) ----
    hist_kernel<<<(N_EDGES + 255) / 256, 256, 0, stream>>>(dst, deg);
    scan_kernel<<<1, 1024, 0, stream>>>(deg, rowptr, deg /*cursor reuse*/);
    fill_kernel<<<(N_EDGES + 255) / 256, 256, 0, stream>>>(src, dst, deg, csr);

    for (int l = 0; l < NLAYERS; l++) {
        const float* hin = (l == 0) ? x : buf_h;
        gather_kernel<<<(N_NODES + 7) / 8, 256, 0, stream>>>(
            hin, rowptr, csr, eps + l, buf_z);
        mlp_kernel<<<(N_NODES + 31) / 32, 256, 0, stream>>>(
            buf_z,
            W1 + (size_t)l * DIM * DIM, b1 + (size_t)l * DIM,
            W2 + (size_t)l * DIM * DIM, b2 + (size_t)l * DIM,
            stats + (size_t)l * 256);
        bnpool_kernel<<<(N_NODES * 32 + 255) / 256, 256, 0, stream>>>(
            buf_z, stats + (size_t)l * 256,
            gamma + (size_t)l * DIM, beta + (size_t)l * DIM,
            batch, buf_h, pools, l);
    }
    final_kernel<<<(N_GRAPHS * NCLASSES + 255) / 256, 256, 0, stream>>>(
        pools, Wlin, blin, out);
}

// Round 3
// 839.512 us; speedup vs baseline: 6.0441x; 1.6356x over previous
//
#include <hip/hip_runtime.h>

#define N_NODES 50000
#define N_EDGES 600000
#define N_GRAPHS 512
#define DIM 128
#define NLAYERS 4
#define NCLASSES 10

// ---------------------------------------------------------------------------
// CSR build step 1: in-degree histogram
// ---------------------------------------------------------------------------
__global__ __launch_bounds__(256) void hist_kernel(
    const int* __restrict__ dst, int* __restrict__ deg)
{
    int e = blockIdx.x * 256 + threadIdx.x;
    if (e >= N_EDGES) return;
    atomicAdd(&deg[dst[e]], 1);
}

// ---------------------------------------------------------------------------
// CSR build step 2: exclusive scan of deg -> rowptr (and cursor copy).
// ---------------------------------------------------------------------------
__global__ __launch_bounds__(1024) void scan_kernel(
    const int* __restrict__ deg, int* __restrict__ rowptr,
    int* __restrict__ cursor)
{
    __shared__ int sums[1024];
    const int CH = (N_NODES + 1023) / 1024;   // 49
    int t = threadIdx.x;
    int begin = t * CH;
    int end = begin + CH; if (end > N_NODES) end = N_NODES;
    int s = 0;
    for (int i = begin; i < end; i++) s += deg[i];
    sums[t] = s;
    __syncthreads();
    for (int off = 1; off < 1024; off <<= 1) {
        int v = (t >= off) ? sums[t - off] : 0;
        __syncthreads();
        sums[t] += v;
        __syncthreads();
    }
    int run = (t == 0) ? 0 : sums[t - 1];
    for (int i = begin; i < end; i++) {
        rowptr[i] = run;
        cursor[i] = run;
        run += deg[i];
    }
    if (t == 1023) rowptr[N_NODES] = run;
}

// ---------------------------------------------------------------------------
// CSR build step 3: scatter edge src ids into their dst's row
// ---------------------------------------------------------------------------
__global__ __launch_bounds__(256) void fill_kernel(
    const int* __restrict__ src, const int* __restrict__ dst,
    int* __restrict__ cursor, int* __restrict__ csr)
{
    int e = blockIdx.x * 256 + threadIdx.x;
    if (e >= N_EDGES) return;
    int p = atomicAdd(&cursor[dst[e]], 1);
    csr[p] = src[e];
}

// ---------------------------------------------------------------------------
// Graph segment boundaries from the sorted batch vector:
// gstart[g] = first node n with batch[n] >= g ; gstart[N_GRAPHS] = N_NODES
// ---------------------------------------------------------------------------
__global__ __launch_bounds__(256) void bounds_kernel(
    const int* __restrict__ batch, int* __restrict__ gstart)
{
    int n = blockIdx.x * 256 + threadIdx.x;
    if (n >= N_NODES) return;
    int b = batch[n];
    int bp = (n == 0) ? -1 : batch[n - 1];
    for (int g = bp + 1; g <= b; g++) gstart[g] = n;
    if (n == N_NODES - 1)
        for (int g = b + 1; g <= N_GRAPHS; g++) gstart[g] = N_NODES;
}

// ---------------------------------------------------------------------------
// Pull-aggregation + GIN self term:  z0[n] = (1+eps)*h[n] + sum_{s in N(n)} h[s]
// ---------------------------------------------------------------------------
__global__ __launch_bounds__(256) void gather_kernel(
    const float* __restrict__ h, const int* __restrict__ rowptr,
    const int* __restrict__ csr, const float* __restrict__ epsP,
    float* __restrict__ z)
{
    int t = threadIdx.x;
    int n = blockIdx.x * 8 + (t >> 5);
    int q = t & 31;
    if (n >= N_NODES) return;
    int beg = rowptr[n], end = rowptr[n + 1];
    float e1 = 1.0f + epsP[0];
    float4 acc = ((const float4*)h)[(size_t)n * 32 + q];
    acc.x *= e1; acc.y *= e1; acc.z *= e1; acc.w *= e1;
    int e = beg;
    for (; e + 1 < end; e += 2) {
        int s0 = csr[e], s1 = csr[e + 1];
        float4 v0 = ((const float4*)h)[(size_t)s0 * 32 + q];
        float4 v1 = ((const float4*)h)[(size_t)s1 * 32 + q];
        acc.x += v0.x + v1.x; acc.y += v0.y + v1.y;
        acc.z += v0.z + v1.z; acc.w += v0.w + v1.w;
    }
    if (e < end) {
        int s0 = csr[e];
        float4 v0 = ((const float4*)h)[(size_t)s0 * 32 + q];
        acc.x += v0.x; acc.y += v0.y; acc.z += v0.z; acc.w += v0.w;
    }
    ((float4*)z)[(size_t)n * 32 + q] = acc;
}

// ---------------------------------------------------------------------------
// Fused GIN MLP with BN-stats epilogue (unchanged from round 2)
// ---------------------------------------------------------------------------
__global__ __launch_bounds__(256) void mlp_kernel(
    float* __restrict__ z,
    const float* __restrict__ W1, const float* __restrict__ b1,
    const float* __restrict__ W2, const float* __restrict__ b2,
    float* __restrict__ stats)
{
    __shared__ float zs[32][129];
    __shared__ float ts[32][129];
    __shared__ float ws[32 * 128];

    const int t   = threadIdx.x;
    const int col = t & 31;
    const int row = t >> 5;
    const int base = blockIdx.x * 32;

    #pragma unroll
    for (int i = 0; i < 4; i++) {
        int nn = i * 8 + row;
        int n = base + nn;
        if (n < N_NODES) {
            float4 av = ((const float4*)z)[(size_t)n * 32 + col];
            zs[nn][col * 4 + 0] = av.x;
            zs[nn][col * 4 + 1] = av.y;
            zs[nn][col * 4 + 2] = av.z;
            zs[nn][col * 4 + 3] = av.w;
        } else {
            zs[nn][col * 4 + 0] = 0.f;
            zs[nn][col * 4 + 1] = 0.f;
            zs[nn][col * 4 + 2] = 0.f;
            zs[nn][col * 4 + 3] = 0.f;
        }
    }

    float acc[4][4];
    #pragma unroll
    for (int j = 0; j < 4; j++)
        #pragma unroll
        for (int c = 0; c < 4; c++) acc[j][c] = 0.f;

    for (int kk = 0; kk < 128; kk += 32) {
        __syncthreads();
        #pragma unroll
        for (int i = 0; i < 4; i++) {
            int f = t + i * 256;
            ((float4*)ws)[f] = ((const float4*)(W1 + (size_t)kk * 128))[f];
        }
        __syncthreads();
        #pragma unroll
        for (int k = 0; k < 32; k++) {
            float4 wv = ((const float4*)(ws + k * 128))[col];
            float z0 = zs[row * 4 + 0][kk + k];
            float z1 = zs[row * 4 + 1][kk + k];
            float z2 = zs[row * 4 + 2][kk + k];
            float z3 = zs[row * 4 + 3][kk + k];
            acc[0][0] += z0 * wv.x; acc[0][1] += z0 * wv.y; acc[0][2] += z0 * wv.z; acc[0][3] += z0 * wv.w;
            acc[1][0] += z1 * wv.x; acc[1][1] += z1 * wv.y; acc[1][2] += z1 * wv.z; acc[1][3] += z1 * wv.w;
            acc[2][0] += z2 * wv.x; acc[2][1] += z2 * wv.y; acc[2][2] += z2 * wv.z; acc[2][3] += z2 * wv.w;
            acc[3][0] += z3 * wv.x; acc[3][1] += z3 * wv.y; acc[3][2] += z3 * wv.z; acc[3][3] += z3 * wv.w;
        }
    }

    {
        float4 b1v = ((const float4*)b1)[col];
        float bb[4] = {b1v.x, b1v.y, b1v.z, b1v.w};
        #pragma unroll
        for (int j = 0; j < 4; j++)
            #pragma unroll
            for (int c = 0; c < 4; c++) {
                float v = acc[j][c] + bb[c];
                ts[row * 4 + j][col * 4 + c] = v > 0.f ? v : 0.f;
                acc[j][c] = 0.f;
            }
    }

    for (int kk = 0; kk < 128; kk += 32) {
        __syncthreads();
        #pragma unroll
        for (int i = 0; i < 4; i++) {
            int f = t + i * 256;
            ((float4*)ws)[f] = ((const float4*)(W2 + (size_t)kk * 128))[f];
        }
        __syncthreads();
        #pragma unroll
        for (int k = 0; k < 32; k++) {
            float4 wv = ((const float4*)(ws + k * 128))[col];
            float t0 = ts[row * 4 + 0][kk + k];
            float t1 = ts[row * 4 + 1][kk + k];
            float t2 = ts[row * 4 + 2][kk + k];
            float t3 = ts[row * 4 + 3][kk + k];
            acc[0][0] += t0 * wv.x; acc[0][1] += t0 * wv.y; acc[0][2] += t0 * wv.z; acc[0][3] += t0 * wv.w;
            acc[1][0] += t1 * wv.x; acc[1][1] += t1 * wv.y; acc[1][2] += t1 * wv.z; acc[1][3] += t1 * wv.w;
            acc[2][0] += t2 * wv.x; acc[2][1] += t2 * wv.y; acc[2][2] += t2 * wv.z; acc[2][3] += t2 * wv.w;
            acc[3][0] += t3 * wv.x; acc[3][1] += t3 * wv.y; acc[3][2] += t3 * wv.z; acc[3][3] += t3 * wv.w;
        }
    }

    float4 b2v = ((const float4*)b2)[col];
    float colsum[4] = {0.f, 0.f, 0.f, 0.f};
    float colsq[4]  = {0.f, 0.f, 0.f, 0.f};
    #pragma unroll
    for (int j = 0; j < 4; j++) {
        int n = base + row * 4 + j;
        float v0 = acc[j][0] + b2v.x;
        float v1 = acc[j][1] + b2v.y;
        float v2 = acc[j][2] + b2v.z;
        float v3 = acc[j][3] + b2v.w;
        if (n < N_NODES) {
            float4 o; o.x = v0; o.y = v1; o.z = v2; o.w = v3;
            ((float4*)z)[(size_t)n * 32 + col] = o;
            colsum[0] += v0; colsq[0] += v0 * v0;
            colsum[1] += v1; colsq[1] += v1 * v1;
            colsum[2] += v2; colsq[2] += v2 * v2;
            colsum[3] += v3; colsq[3] += v3 * v3;
        }
    }

    __syncthreads();
    float* sc = &zs[0][0];
    #pragma unroll
    for (int c = 0; c < 4; c++) {
        sc[row * 128 + col * 4 + c]        = colsum[c];
        sc[1024 + row * 128 + col * 4 + c] = colsq[c];
    }
    __syncthreads();
    if (t < 128) {
        float s = 0.f, q2 = 0.f;
        #pragma unroll
        for (int r = 0; r < 8; r++) {
            s  += sc[r * 128 + t];
            q2 += sc[1024 + r * 128 + t];
        }
        unsafeAtomicAdd(&stats[t], s);
        unsafeAtomicAdd(&stats[128 + t], q2);
    }
}

// ---------------------------------------------------------------------------
// BN apply + ReLU + write h + pool: ONE BLOCK PER GRAPH, zero atomics.
// batch is sorted -> graph g owns contiguous nodes [gstart[g], gstart[g+1]).
// Thread (r=t>>5, q=t&31): node-lane r (stride 8), channels 4q..4q+3.
// ---------------------------------------------------------------------------
__global__ __launch_bounds__(256) void bnpool_kernel(
    const float* __restrict__ z, const float* __restrict__ stats,
    const float* __restrict__ gamma, const float* __restrict__ beta,
    const int* __restrict__ gstart, float* __restrict__ hout,
    float* __restrict__ pools, int layer)
{
    __shared__ float red[8][128];
    const int g = blockIdx.x;
    const int t = threadIdx.x;
    const int q = t & 31, r = t >> 5;
    const int beg = gstart[g], end = gstart[g + 1];

    float4 s  = ((const float4*)stats)[q];
    float4 sq = ((const float4*)stats)[32 + q];
    float4 gm = ((const float4*)gamma)[q];
    float4 bt = ((const float4*)beta)[q];
    const float invN = 1.0f / (float)N_NODES;
    float m, vr;
    float4 scl, sh;
    m = s.x * invN; vr = sq.x * invN - m * m; scl.x = gm.x * rsqrtf(vr + 1e-5f); sh.x = bt.x - m * scl.x;
    m = s.y * invN; vr = sq.y * invN - m * m; scl.y = gm.y * rsqrtf(vr + 1e-5f); sh.y = bt.y - m * scl.y;
    m = s.z * invN; vr = sq.z * invN - m * m; scl.z = gm.z * rsqrtf(vr + 1e-5f); sh.z = bt.z - m * scl.z;
    m = s.w * invN; vr = sq.w * invN - m * m; scl.w = gm.w * rsqrtf(vr + 1e-5f); sh.w = bt.w - m * scl.w;

    float4 acc = {0.f, 0.f, 0.f, 0.f};
    for (int n = beg + r; n < end; n += 8) {
        float4 zv = ((const float4*)z)[(size_t)n * 32 + q];
        float4 hv;
        hv.x = fmaxf(zv.x * scl.x + sh.x, 0.f);
        hv.y = fmaxf(zv.y * scl.y + sh.y, 0.f);
        hv.z = fmaxf(zv.z * scl.z + sh.z, 0.f);
        hv.w = fmaxf(zv.w * scl.w + sh.w, 0.f);
        ((float4*)hout)[(size_t)n * 32 + q] = hv;
        acc.x += hv.x; acc.y += hv.y; acc.z += hv.z; acc.w += hv.w;
    }
    red[r][q * 4 + 0] = acc.x;
    red[r][q * 4 + 1] = acc.y;
    red[r][q * 4 + 2] = acc.z;
    red[r][q * 4 + 3] = acc.w;
    __syncthreads();
    if (t < 128) {
        float sm = 0.f;
        #pragma unroll
        for (int rr = 0; rr < 8; rr++) sm += red[rr][t];
        pools[(size_t)g * (DIM * NLAYERS) + (size_t)layer * DIM + t] = sm;
    }
}

// ---------------------------------------------------------------------------
// Final linear head
// ---------------------------------------------------------------------------
__global__ __launch_bounds__(256) void final_kernel(
    const float* __restrict__ pools, const float* __restrict__ Wlin,
    const float* __restrict__ blin, float* __restrict__ out)
{
    int idx = blockIdx.x * 256 + threadIdx.x;
    if (idx >= N_GRAPHS * NCLASSES) return;
    int g = idx / NCLASSES, o = idx % NCLASSES;
    const float* xr = pools + (size_t)g * (DIM * NLAYERS);
    float acc = blin[o];
    for (int k = 0; k < DIM * NLAYERS; k++)
        acc += xr[k] * Wlin[(size_t)k * NCLASSES + o];
    out[idx] = acc;
}

// ---------------------------------------------------------------------------
extern "C" void kernel_launch(void* const* d_in, const int* in_sizes, int n_in,
                              void* d_out, int out_size, void* d_ws, size_t ws_size,
                              hipStream_t stream)
{
    const float* x     = (const float*)d_in[0];
    const int*   src   = (const int*)d_in[1];
    const int*   dst   = ((const int*)d_in[1]) + N_EDGES;
    const int*   batch = (const int*)d_in[2];
    const float* W1    = (const float*)d_in[3];
    const float* b1    = (const float*)d_in[4];
    const float* W2    = (const float*)d_in[5];
    const float* b2    = (const float*)d_in[6];
    const float* eps   = (const float*)d_in[7];
    const float* gamma = (const float*)d_in[8];
    const float* beta  = (const float*)d_in[9];
    const float* Wlin  = (const float*)d_in[10];
    const float* blin  = (const float*)d_in[11];
    float* out = (float*)d_out;

    char* ws = (char*)d_ws;
    const size_t FEAT = (size_t)N_NODES * DIM * sizeof(float);       // 25.6 MB
    size_t off = 0;
    float* buf_h  = (float*)(ws + off); off += FEAT;
    float* buf_z  = (float*)(ws + off); off += FEAT;
    float* pools  = (float*)(ws + off); off += (size_t)N_GRAPHS * DIM * NLAYERS * sizeof(float);
    float* stats  = (float*)(ws + off); off += (size_t)NLAYERS * 256 * sizeof(float);
    int*   deg    = (int*)(ws + off);   off += (size_t)N_NODES * sizeof(int);      // also "cursor"
    int*   rowptr = (int*)(ws + off);   off += (size_t)(N_NODES + 1) * sizeof(int) + 12;
    int*   csr    = (int*)(ws + off);   off += (size_t)N_EDGES * sizeof(int);
    int*   gstart = (int*)(ws + off);   off += (size_t)(N_GRAPHS + 1) * sizeof(int);

    // zero BN-stats accumulators and degree histogram
    hipMemsetAsync(stats, 0, (size_t)NLAYERS * 256 * sizeof(float), stream);
    hipMemsetAsync(deg, 0, (size_t)N_NODES * sizeof(int), stream);

    // ---- build CSR + graph bounds once (reused across all 4 layers) ----
    hist_kernel<<<(N_EDGES + 255) / 256, 256, 0, stream>>>(dst, deg);
    scan_kernel<<<1, 1024, 0, stream>>>(deg, rowptr, deg /*cursor reuse*/);
    fill_kernel<<<(N_EDGES + 255) / 256, 256, 0, stream>>>(src, dst, deg, csr);
    bounds_kernel<<<(N_NODES + 255) / 256, 256, 0, stream>>>(batch, gstart);

    for (int l = 0; l < NLAYERS; l++) {
        const float* hin = (l == 0) ? x : buf_h;
        gather_kernel<<<(N_NODES + 7) / 8, 256, 0, stream>>>(
            hin, rowptr, csr, eps + l, buf_z);
        mlp_kernel<<<(N_NODES + 31) / 32, 256, 0, stream>>>(
            buf_z,
            W1 + (size_t)l * DIM * DIM, b1 + (size_t)l * DIM,
            W2 + (size_t)l * DIM * DIM, b2 + (size_t)l * DIM,
            stats + (size_t)l * 256);
        bnpool_kernel<<<N_GRAPHS, 256, 0, stream>>>(
            buf_z, stats + (size_t)l * 256,
            gamma + (size_t)l * DIM, beta + (size_t)l * DIM,
            gstart, buf_h, pools, l);
    }
    final_kernel<<<(N_GRAPHS * NCLASSES + 255) / 256, 256, 0, stream>>>(
        pools, Wlin, blin, out);
}

// Round 4
// 634.490 us; speedup vs baseline: 7.9971x; 1.3231x over previous
//
#include <hip/hip_runtime.h>

#define N_NODES 50000
#define N_EDGES 600000
#define N_GRAPHS 512
#define DIM 128
#define NLAYERS 4
#define NCLASSES 10
#define KP 136   // padded LDS k-stride in bf16 elems (272 B, 16B-aligned, 2-way-conflict-free)

typedef __attribute__((ext_vector_type(8))) short short8;
typedef __attribute__((ext_vector_type(4))) float f32x4;

// ---- fp32 -> bf16 (RNE) helpers ----
__device__ inline unsigned short f2bf(float v) {
    union { float f; unsigned u; } c; c.f = v;
    unsigned u = c.u;
    u += 0x7FFFu + ((u >> 16) & 1u);
    return (unsigned short)(u >> 16);
}
__device__ inline float bf2f(unsigned short h) {
    union { float f; unsigned u; } c; c.u = ((unsigned)h) << 16;
    return c.f;
}

// ---------------------------------------------------------------------------
// CSR build step 1: in-degree histogram
// ---------------------------------------------------------------------------
__global__ __launch_bounds__(256) void hist_kernel(
    const int* __restrict__ dst, int* __restrict__ deg)
{
    int e = blockIdx.x * 256 + threadIdx.x;
    if (e >= N_EDGES) return;
    atomicAdd(&deg[dst[e]], 1);
}

// ---------------------------------------------------------------------------
// Hierarchical scan of deg -> rowptr/cursor. 50000 ints = 12500 int4.
// scan1: per-block (256 int4 = 1024 ints) sums. 49 blocks.
// ---------------------------------------------------------------------------
__global__ __launch_bounds__(256) void scan1_kernel(
    const int* __restrict__ deg, int* __restrict__ bsum)
{
    __shared__ int red[256];
    int t = threadIdx.x;
    int i4 = blockIdx.x * 256 + t;
    int s = 0;
    if (i4 < 12500) {
        int4 v = ((const int4*)deg)[i4];
        s = v.x + v.y + v.z + v.w;
    }
    red[t] = s;
    __syncthreads();
    for (int off = 128; off > 0; off >>= 1) {
        if (t < off) red[t] += red[t + off];
        __syncthreads();
    }
    if (t == 0) bsum[blockIdx.x] = red[0];
}

__global__ __launch_bounds__(64) void scan2_kernel(int* __restrict__ bsum)
{
    __shared__ int sh[64];
    int t = threadIdx.x;
    sh[t] = (t < 49) ? bsum[t] : 0;
    __syncthreads();
    if (t == 0) {
        int run = 0;
        for (int i = 0; i < 49; i++) { int v = sh[i]; sh[i] = run; run += v; }
    }
    __syncthreads();
    if (t < 49) bsum[t] = sh[t];
}

__global__ __launch_bounds__(256) void scan3_kernel(
    const int* __restrict__ deg, const int* __restrict__ bsum,
    int* __restrict__ rowptr, int* __restrict__ cursor)
{
    __shared__ int red[256];
    int t = threadIdx.x;
    int i4 = blockIdx.x * 256 + t;
    int4 v = {0, 0, 0, 0};
    if (i4 < 12500) v = ((const int4*)deg)[i4];
    int s = v.x + v.y + v.z + v.w;
    red[t] = s;
    __syncthreads();
    for (int off = 1; off < 256; off <<= 1) {
        int val = (t >= off) ? red[t - off] : 0;
        __syncthreads();
        red[t] += val;
        __syncthreads();
    }
    int run = bsum[blockIdx.x] + (t ? red[t - 1] : 0);
    if (i4 < 12500) {
        int4 rp;
        rp.x = run; run += v.x;
        rp.y = run; run += v.y;
        rp.z = run; run += v.z;
        rp.w = run; run += v.w;
        ((int4*)rowptr)[i4] = rp;   // cursor==deg aliasing OK: v loaded before any write
        ((int4*)cursor)[i4] = rp;
    }
    if (blockIdx.x == 0 && t == 0) rowptr[N_NODES] = N_EDGES;
}

// ---------------------------------------------------------------------------
// CSR build step 3: scatter edge src ids into their dst's row
// ---------------------------------------------------------------------------
__global__ __launch_bounds__(256) void fill_kernel(
    const int* __restrict__ src, const int* __restrict__ dst,
    int* __restrict__ cursor, int* __restrict__ csr)
{
    int e = blockIdx.x * 256 + threadIdx.x;
    if (e >= N_EDGES) return;
    int p = atomicAdd(&cursor[dst[e]], 1);
    csr[p] = src[e];
}

// ---------------------------------------------------------------------------
// Graph segment boundaries from the sorted batch vector
// ---------------------------------------------------------------------------
__global__ __launch_bounds__(256) void bounds_kernel(
    const int* __restrict__ batch, int* __restrict__ gstart)
{
    int n = blockIdx.x * 256 + threadIdx.x;
    if (n >= N_NODES) return;
    int b = batch[n];
    int bp = (n == 0) ? -1 : batch[n - 1];
    for (int g = bp + 1; g <= b; g++) gstart[g] = n;
    if (n == N_NODES - 1)
        for (int g = b + 1; g <= N_GRAPHS; g++) gstart[g] = N_NODES;
}

// ---------------------------------------------------------------------------
// Pre-swizzle W1/W2 (all layers) into MFMA B-fragment order, split hi/lo bf16.
// Fragment addressing: whi[ l*32768 + w01*16384 + ((ks*8+cg)*64+lane)*8 + j ]
//   = W[k = ks*32 + (lane>>4)*8 + j][n = cg*16 + (lane&15)]
// ---------------------------------------------------------------------------
__global__ __launch_bounds__(256) void wconv_kernel(
    const float* __restrict__ W1, const float* __restrict__ W2,
    unsigned short* __restrict__ whi, unsigned short* __restrict__ wlo)
{
    int idx = blockIdx.x * 256 + threadIdx.x;
    if (idx >= NLAYERS * 2 * 16384) return;
    int f   = idx & 16383;
    int w01 = (idx >> 14) & 1;
    int l   = idx >> 15;
    int j    = f & 7;
    int lane = (f >> 3) & 63;
    int cg   = (f >> 9) & 7;
    int ks   = f >> 12;
    int k = ks * 32 + (lane >> 4) * 8 + j;
    int n = cg * 16 + (lane & 15);
    const float* W = (w01 == 0 ? W1 : W2) + (size_t)l * 16384;
    float v = W[k * 128 + n];
    unsigned short hi = f2bf(v);
    unsigned short lo = f2bf(v - bf2f(hi));
    whi[idx] = hi;
    wlo[idx] = lo;
}

// ---------------------------------------------------------------------------
// MFMA MLP: z = (relu(z0@W1+b1))@W2 + b2, split-bf16 (hi+lo, 3 MFMAs/tile)
// Block: 32 nodes x 128 cols, 4 waves. Wave w: rows 16*(w&1).., cols 64*(w>>1)..
// A staged in LDS [m][k] (KP stride); B fragments straight from global whi/wlo.
// BN sum/sumsq epilogue -> global atomics.
// ---------------------------------------------------------------------------
__global__ __launch_bounds__(256) void mlp_mfma_kernel(
    float* __restrict__ z,
    const unsigned short* __restrict__ whi, const unsigned short* __restrict__ wlo,
    const float* __restrict__ b1, const float* __restrict__ b2,
    float* __restrict__ stats)
{
    __shared__ unsigned short zhi[32 * KP], zlo[32 * KP];
    __shared__ unsigned short thi[32 * KP], tlo[32 * KP];

    const int t = threadIdx.x;
    const int lane = t & 63;
    const int w = t >> 6;
    const int wr = w & 1, wc = w >> 1;
    const int l15 = lane & 15, quad = lane >> 4;
    const int base = blockIdx.x * 32;

    // ---- stage z0 tile as hi/lo bf16, A-fragment layout [m][k] ----
    {
        int m  = t >> 3;
        int kb = (t & 7) * 16;
        int n  = base + m;
        unsigned short hi[16], lo[16];
        if (n < N_NODES) {
            const float4* srcp = (const float4*)(z + (size_t)n * 128 + kb);
            #pragma unroll
            for (int i = 0; i < 4; i++) {
                float4 v = srcp[i];
                float vv[4] = {v.x, v.y, v.z, v.w};
                #pragma unroll
                for (int c = 0; c < 4; c++) {
                    unsigned short h = f2bf(vv[c]);
                    hi[i * 4 + c] = h;
                    lo[i * 4 + c] = f2bf(vv[c] - bf2f(h));
                }
            }
        } else {
            #pragma unroll
            for (int i = 0; i < 16; i++) { hi[i] = 0; lo[i] = 0; }
        }
        *((short8*)&zhi[m * KP + kb])     = *((short8*)&hi[0]);
        *((short8*)&zhi[m * KP + kb + 8]) = *((short8*)&hi[8]);
        *((short8*)&zlo[m * KP + kb])     = *((short8*)&lo[0]);
        *((short8*)&zlo[m * KP + kb + 8]) = *((short8*)&lo[8]);
    }
    __syncthreads();

    f32x4 acc[4];
    #pragma unroll
    for (int i = 0; i < 4; i++) acc[i] = (f32x4){0.f, 0.f, 0.f, 0.f};

    const int arow = (16 * wr + l15) * KP;

    // ---- GEMM1: z0 @ W1 ----
    #pragma unroll
    for (int ks = 0; ks < 4; ks++) {
        int ak = ks * 32 + quad * 8;
        short8 ahi = *((short8*)&zhi[arow + ak]);
        short8 alo = *((short8*)&zlo[arow + ak]);
        #pragma unroll
        for (int i = 0; i < 4; i++) {
            int cg = wc * 4 + i;
            size_t woff = (size_t)(((ks * 8 + cg) * 64 + lane) * 8);
            short8 bhi = *((const short8*)&whi[woff]);
            short8 blo = *((const short8*)&wlo[woff]);
            acc[i] = __builtin_amdgcn_mfma_f32_16x16x32_bf16(alo, bhi, acc[i], 0, 0, 0);
            acc[i] = __builtin_amdgcn_mfma_f32_16x16x32_bf16(ahi, blo, acc[i], 0, 0, 0);
            acc[i] = __builtin_amdgcn_mfma_f32_16x16x32_bf16(ahi, bhi, acc[i], 0, 0, 0);
        }
    }

    // ---- bias + relu -> t (LDS, A-layout, hi/lo) ----
    #pragma unroll
    for (int i = 0; i < 4; i++) {
        int col = wc * 64 + i * 16 + l15;
        float bb = b1[col];
        #pragma unroll
        for (int r = 0; r < 4; r++) {
            int m = 16 * wr + quad * 4 + r;
            float v = acc[i][r] + bb;
            v = v > 0.f ? v : 0.f;
            unsigned short h = f2bf(v);
            thi[m * KP + col] = h;
            tlo[m * KP + col] = f2bf(v - bf2f(h));
        }
        acc[i] = (f32x4){0.f, 0.f, 0.f, 0.f};
    }
    __syncthreads();   // t visible to all; zhi/zlo now dead (scratch below)

    // ---- GEMM2: t @ W2 ----
    const unsigned short* w2hi = whi + 16384;
    const unsigned short* w2lo = wlo + 16384;
    #pragma unroll
    for (int ks = 0; ks < 4; ks++) {
        int ak = ks * 32 + quad * 8;
        short8 ahi = *((short8*)&thi[arow + ak]);
        short8 alo = *((short8*)&tlo[arow + ak]);
        #pragma unroll
        for (int i = 0; i < 4; i++) {
            int cg = wc * 4 + i;
            size_t woff = (size_t)(((ks * 8 + cg) * 64 + lane) * 8);
            short8 bhi = *((const short8*)&w2hi[woff]);
            short8 blo = *((const short8*)&w2lo[woff]);
            acc[i] = __builtin_amdgcn_mfma_f32_16x16x32_bf16(alo, bhi, acc[i], 0, 0, 0);
            acc[i] = __builtin_amdgcn_mfma_f32_16x16x32_bf16(ahi, blo, acc[i], 0, 0, 0);
            acc[i] = __builtin_amdgcn_mfma_f32_16x16x32_bf16(ahi, bhi, acc[i], 0, 0, 0);
        }
    }

    // ---- bias + store z + BN partials ----
    float csum[4], csq[4];
    #pragma unroll
    for (int i = 0; i < 4; i++) {
        int col = wc * 64 + i * 16 + l15;
        float bb = b2[col];
        float s = 0.f, q2 = 0.f;
        #pragma unroll
        for (int r = 0; r < 4; r++) {
            int m = 16 * wr + quad * 4 + r;
            int n = base + m;
            float v = acc[i][r] + bb;
            if (n < N_NODES) {
                z[(size_t)n * 128 + col] = v;
                s += v; q2 += v * v;
            }
        }
        csum[i] = s; csq[i] = q2;
    }

    // ---- block stats reduction (reuse zhi/zlo as float scratch) ----
    float* sums = (float*)zhi;   // 1024 floats
    float* sqs  = (float*)zlo;   // 1024 floats
    #pragma unroll
    for (int i = 0; i < 4; i++) {
        sums[(w * 4 + i) * 64 + lane] = csum[i];
        sqs [(w * 4 + i) * 64 + lane] = csq[i];
    }
    __syncthreads();
    if (t < 128) {
        int c = t;
        int wcc = c >> 6, ci = (c >> 4) & 3, cl = c & 15;
        float s = 0.f, q2 = 0.f;
        #pragma unroll
        for (int wrr = 0; wrr < 2; wrr++) {
            int ww = wcc * 2 + wrr;
            #pragma unroll
            for (int u = 0; u < 4; u++) {
                int ln = cl + u * 16;
                s  += sums[(ww * 4 + ci) * 64 + ln];
                q2 += sqs [(ww * 4 + ci) * 64 + ln];
            }
        }
        unsafeAtomicAdd(&stats[c], s);
        unsafeAtomicAdd(&stats[128 + c], q2);
    }
}

// ---------------------------------------------------------------------------
// Pull-aggregation + GIN self term
// ---------------------------------------------------------------------------
__global__ __launch_bounds__(256) void gather_kernel(
    const float* __restrict__ h, const int* __restrict__ rowptr,
    const int* __restrict__ csr, const float* __restrict__ epsP,
    float* __restrict__ z)
{
    int t = threadIdx.x;
    int n = blockIdx.x * 8 + (t >> 5);
    int q = t & 31;
    if (n >= N_NODES) return;
    int beg = rowptr[n], end = rowptr[n + 1];
    float e1 = 1.0f + epsP[0];
    float4 acc = ((const float4*)h)[(size_t)n * 32 + q];
    acc.x *= e1; acc.y *= e1; acc.z *= e1; acc.w *= e1;
    int e = beg;
    for (; e + 1 < end; e += 2) {
        int s0 = csr[e], s1 = csr[e + 1];
        float4 v0 = ((const float4*)h)[(size_t)s0 * 32 + q];
        float4 v1 = ((const float4*)h)[(size_t)s1 * 32 + q];
        acc.x += v0.x + v1.x; acc.y += v0.y + v1.y;
        acc.z += v0.z + v1.z; acc.w += v0.w + v1.w;
    }
    if (e < end) {
        int s0 = csr[e];
        float4 v0 = ((const float4*)h)[(size_t)s0 * 32 + q];
        acc.x += v0.x; acc.y += v0.y; acc.z += v0.z; acc.w += v0.w;
    }
    ((float4*)z)[(size_t)n * 32 + q] = acc;
}

// ---------------------------------------------------------------------------
// BN apply + ReLU + write h + pool: one block per graph, zero atomics
// ---------------------------------------------------------------------------
__global__ __launch_bounds__(256) void bnpool_kernel(
    const float* __restrict__ z, const float* __restrict__ stats,
    const float* __restrict__ gamma, const float* __restrict__ beta,
    const int* __restrict__ gstart, float* __restrict__ hout,
    float* __restrict__ pools, int layer)
{
    __shared__ float red[8][128];
    const int g = blockIdx.x;
    const int t = threadIdx.x;
    const int q = t & 31, r = t >> 5;
    const int beg = gstart[g], end = gstart[g + 1];

    float4 s  = ((const float4*)stats)[q];
    float4 sq = ((const float4*)stats)[32 + q];
    float4 gm = ((const float4*)gamma)[q];
    float4 bt = ((const float4*)beta)[q];
    const float invN = 1.0f / (float)N_NODES;
    float m, vr;
    float4 scl, sh;
    m = s.x * invN; vr = sq.x * invN - m * m; scl.x = gm.x * rsqrtf(vr + 1e-5f); sh.x = bt.x - m * scl.x;
    m = s.y * invN; vr = sq.y * invN - m * m; scl.y = gm.y * rsqrtf(vr + 1e-5f); sh.y = bt.y - m * scl.y;
    m = s.z * invN; vr = sq.z * invN - m * m; scl.z = gm.z * rsqrtf(vr + 1e-5f); sh.z = bt.z - m * scl.z;
    m = s.w * invN; vr = sq.w * invN - m * m; scl.w = gm.w * rsqrtf(vr + 1e-5f); sh.w = bt.w - m * scl.w;

    float4 acc = {0.f, 0.f, 0.f, 0.f};
    for (int n = beg + r; n < end; n += 8) {
        float4 zv = ((const float4*)z)[(size_t)n * 32 + q];
        float4 hv;
        hv.x = fmaxf(zv.x * scl.x + sh.x, 0.f);
        hv.y = fmaxf(zv.y * scl.y + sh.y, 0.f);
        hv.z = fmaxf(zv.z * scl.z + sh.z, 0.f);
        hv.w = fmaxf(zv.w * scl.w + sh.w, 0.f);
        ((float4*)hout)[(size_t)n * 32 + q] = hv;
        acc.x += hv.x; acc.y += hv.y; acc.z += hv.z; acc.w += hv.w;
    }
    red[r][q * 4 + 0] = acc.x;
    red[r][q * 4 + 1] = acc.y;
    red[r][q * 4 + 2] = acc.z;
    red[r][q * 4 + 3] = acc.w;
    __syncthreads();
    if (t < 128) {
        float sm = 0.f;
        #pragma unroll
        for (int rr = 0; rr < 8; rr++) sm += red[rr][t];
        pools[(size_t)g * (DIM * NLAYERS) + (size_t)layer * DIM + t] = sm;
    }
}

// ---------------------------------------------------------------------------
// Final linear head
// ---------------------------------------------------------------------------
__global__ __launch_bounds__(256) void final_kernel(
    const float* __restrict__ pools, const float* __restrict__ Wlin,
    const float* __restrict__ blin, float* __restrict__ out)
{
    int idx = blockIdx.x * 256 + threadIdx.x;
    if (idx >= N_GRAPHS * NCLASSES) return;
    int g = idx / NCLASSES, o = idx % NCLASSES;
    const float* xr = pools + (size_t)g * (DIM * NLAYERS);
    float acc = blin[o];
    for (int k = 0; k < DIM * NLAYERS; k++)
        acc += xr[k] * Wlin[(size_t)k * NCLASSES + o];
    out[idx] = acc;
}

// ---------------------------------------------------------------------------
extern "C" void kernel_launch(void* const* d_in, const int* in_sizes, int n_in,
                              void* d_out, int out_size, void* d_ws, size_t ws_size,
                              hipStream_t stream)
{
    const float* x     = (const float*)d_in[0];
    const int*   src   = (const int*)d_in[1];
    const int*   dst   = ((const int*)d_in[1]) + N_EDGES;
    const int*   batch = (const int*)d_in[2];
    const float* W1    = (const float*)d_in[3];
    const float* b1    = (const float*)d_in[4];
    const float* W2    = (const float*)d_in[5];
    const float* b2    = (const float*)d_in[6];
    const float* eps   = (const float*)d_in[7];
    const float* gamma = (const float*)d_in[8];
    const float* beta  = (const float*)d_in[9];
    const float* Wlin  = (const float*)d_in[10];
    const float* blin  = (const float*)d_in[11];
    float* out = (float*)d_out;

    char* ws = (char*)d_ws;
    const size_t FEAT = (size_t)N_NODES * DIM * sizeof(float);       // 25.6 MB
    size_t off = 0;
    float* buf_h  = (float*)(ws + off); off += FEAT;
    float* buf_z  = (float*)(ws + off); off += FEAT;
    float* pools  = (float*)(ws + off); off += (size_t)N_GRAPHS * DIM * NLAYERS * sizeof(float);
    float* stats  = (float*)(ws + off); off += (size_t)NLAYERS * 256 * sizeof(float);
    int*   deg    = (int*)(ws + off);   off += (size_t)N_NODES * sizeof(int);      // also "cursor"
    int*   rowptr = (int*)(ws + off);   off += (size_t)(N_NODES + 1) * sizeof(int) + 12;
    int*   csr    = (int*)(ws + off);   off += (size_t)N_EDGES * sizeof(int);
    int*   gstart = (int*)(ws + off);   off += 2064;     // 513 ints, padded
    int*   bsum   = (int*)(ws + off);   off += 208;      // 49 ints, padded
    unsigned short* whi = (unsigned short*)(ws + off); off += (size_t)NLAYERS * 2 * 16384 * 2;
    unsigned short* wlo = (unsigned short*)(ws + off); off += (size_t)NLAYERS * 2 * 16384 * 2;

    hipMemsetAsync(stats, 0, (size_t)NLAYERS * 256 * sizeof(float), stream);
    hipMemsetAsync(deg, 0, (size_t)N_NODES * sizeof(int), stream);

    // ---- once per call: CSR, graph bounds, weight pre-swizzle ----
    hist_kernel<<<(N_EDGES + 255) / 256, 256, 0, stream>>>(dst, deg);
    scan1_kernel<<<49, 256, 0, stream>>>(deg, bsum);
    scan2_kernel<<<1, 64, 0, stream>>>(bsum);
    scan3_kernel<<<49, 256, 0, stream>>>(deg, bsum, rowptr, deg /*cursor*/);
    fill_kernel<<<(N_EDGES + 255) / 256, 256, 0, stream>>>(src, dst, deg, csr);
    bounds_kernel<<<(N_NODES + 255) / 256, 256, 0, stream>>>(batch, gstart);
    wconv_kernel<<<(NLAYERS * 2 * 16384 + 255) / 256, 256, 0, stream>>>(W1, W2, whi, wlo);

    for (int l = 0; l < NLAYERS; l++) {
        const float* hin = (l == 0) ? x : buf_h;
        gather_kernel<<<(N_NODES + 7) / 8, 256, 0, stream>>>(
            hin, rowptr, csr, eps + l, buf_z);
        mlp_mfma_kernel<<<(N_NODES + 31) / 32, 256, 0, stream>>>(
            buf_z,
            whi + (size_t)l * 32768, wlo + (size_t)l * 32768,
            b1 + (size_t)l * DIM, b2 + (size_t)l * DIM,
            stats + (size_t)l * 256);
        bnpool_kernel<<<N_GRAPHS, 256, 0, stream>>>(
            buf_z, stats + (size_t)l * 256,
            gamma + (size_t)l * DIM, beta + (size_t)l * DIM,
            gstart, buf_h, pools, l);
    }
    final_kernel<<<(N_GRAPHS * NCLASSES + 255) / 256, 256, 0, stream>>>(
        pools, Wlin, blin, out);
}